// Round 6
// baseline (1145.276 us; speedup 1.0000x reference)
//
#include <hip/hip_runtime.h>
#include <math.h>

typedef __attribute__((ext_vector_type(8))) short short8;
typedef __attribute__((ext_vector_type(4))) float f32x4;
typedef __attribute__((ext_vector_type(4))) unsigned short us4;

constexpr int NSEG = 16;
constexpr int CC   = 768;
constexpr int PP   = 197;
constexpr int NH   = 12;
constexpr int HD   = 64;
constexpr int NT   = 512;
constexpr int MN   = NT * CC;
constexpr float LN_EPS = 1e-5f;

// pass-through copy geometry, in float4 units (p>=1 rows of every token)
constexpr unsigned CPT  = 196 * CC / 4;          // 37632
constexpr unsigned TOK4 = PP * CC / 4;           // 37824
constexpr unsigned ROW4 = CC / 4;                // 192
constexpr unsigned W4TOT = (unsigned)NT * CPT;   // 19267584
constexpr unsigned CHUNK = 256;                  // float4 per wave-grab (4 KB)

__device__ inline unsigned short f2bf(float f) {
    unsigned u = __float_as_uint(f);
    u += 0x7fffu + ((u >> 16) & 1u);
    return (unsigned short)(u >> 16);
}

__device__ inline unsigned cidx(unsigned i) {
    unsigned t = i / CPT;                 // magic-mul div
    return i + t * ROW4 + ROW4;
}

// dynamic wave-level chunked copy: self-balancing across blocks/CUs
__device__ inline void copy_dyn(const float* __restrict__ xf, float* __restrict__ of,
                                unsigned* __restrict__ ctr, unsigned base, unsigned len) {
    const f32x4* __restrict__ x4 = (const f32x4*)xf;
    f32x4* __restrict__ o4 = (f32x4*)of;
    int lane = threadIdx.x & 63;
    while (true) {
        unsigned idx = 0;
        if (lane == 0) idx = atomicAdd(ctr, CHUNK);
        idx = (unsigned)__shfl((int)idx, 0);
        if (idx >= len) break;
        unsigned r0 = idx + lane;
        unsigned r1 = r0 + 64, r2 = r0 + 128, r3 = r0 + 192;
        bool p0 = r0 < len, p1 = r1 < len, p2 = r2 < len, p3 = r3 < len;
        unsigned a0 = p0 ? cidx(base + r0) : 0u;
        unsigned a1 = p1 ? cidx(base + r1) : 0u;
        unsigned a2 = p2 ? cidx(base + r2) : 0u;
        unsigned a3 = p3 ? cidx(base + r3) : 0u;
        f32x4 v0, v1, v2, v3;
        if (p0) v0 = __builtin_nontemporal_load(x4 + a0);
        if (p1) v1 = __builtin_nontemporal_load(x4 + a1);
        if (p2) v2 = __builtin_nontemporal_load(x4 + a2);
        if (p3) v3 = __builtin_nontemporal_load(x4 + a3);
        if (p0) __builtin_nontemporal_store(v0, o4 + a0);
        if (p1) __builtin_nontemporal_store(v1, o4 + a1);
        if (p2) __builtin_nontemporal_store(v2, o4 + a2);
        if (p3) __builtin_nontemporal_store(v3, o4 + a3);
    }
}

// ---------------- 64x64 MFMA bf16 tile, 4 waves, fragments direct from global ----------------
template<bool ADD_RES>
__device__ inline void gemm_tile(const unsigned short* __restrict__ A,
                                 const unsigned short* __restrict__ Bt,   // [n][k]
                                 const float* __restrict__ bias,
                                 const float* __restrict__ res,
                                 float* __restrict__ outp,
                                 int by, int bx, size_t orow) {
    int tid  = threadIdx.x;
    int lane = tid & 63, wv = tid >> 6;
    int wr = wv >> 1, wc = wv & 1;
    int l15 = lane & 15, lh = lane >> 4;
    int m0 = by * 64 + wr * 32;
    int n0 = bx * 64 + wc * 32;
    f32x4 acc[2][2] = {};
    const unsigned short* Ar0 = A  + (size_t)(m0 + l15) * CC + lh * 8;
    const unsigned short* Ar1 = Ar0 + 16 * CC;
    const unsigned short* Br0 = Bt + (size_t)(n0 + l15) * CC + lh * 8;
    const unsigned short* Br1 = Br0 + 16 * CC;
    #pragma unroll 4
    for (int k0 = 0; k0 < CC; k0 += 32) {
        short8 a0 = *(const short8*)(Ar0 + k0);
        short8 a1 = *(const short8*)(Ar1 + k0);
        short8 b0 = *(const short8*)(Br0 + k0);
        short8 b1 = *(const short8*)(Br1 + k0);
        acc[0][0] = __builtin_amdgcn_mfma_f32_16x16x32_bf16(a0, b0, acc[0][0], 0, 0, 0);
        acc[0][1] = __builtin_amdgcn_mfma_f32_16x16x32_bf16(a0, b1, acc[0][1], 0, 0, 0);
        acc[1][0] = __builtin_amdgcn_mfma_f32_16x16x32_bf16(a1, b0, acc[1][0], 0, 0, 0);
        acc[1][1] = __builtin_amdgcn_mfma_f32_16x16x32_bf16(a1, b1, acc[1][1], 0, 0, 0);
    }
    #pragma unroll
    for (int mf = 0; mf < 2; ++mf)
        #pragma unroll
        for (int nf = 0; nf < 2; ++nf)
            #pragma unroll
            for (int r = 0; r < 4; ++r) {
                int row = m0 + mf * 16 + lh * 4 + r;
                int col = n0 + nf * 16 + l15;
                float v = acc[mf][nf][r] + bias[col];
                if (ADD_RES) v += res[(size_t)row * CC + col];
                outp[(size_t)row * orow + col] = v;
            }
}

// slice layout (float4 units)
constexpr unsigned B1 = 0,           L1 = 5000192u;
constexpr unsigned B2 = L1,          L2 = 5300224u;
constexpr unsigned B3 = B2 + L2,     L3 = 5300224u;
constexpr unsigned B4 = B3 + L3,     L4 = W4TOT - B4;   // 3666944

// ================= K1: LN (512) | weight cvt x3 (768) | copy (768) =================
constexpr int K1_LN = NT, K1_CVT = 768, K1_CPY = 768;
__global__ __launch_bounds__(256) void k1(const float* __restrict__ x, const float* __restrict__ w1,
        const float* __restrict__ g, const float* __restrict__ bln,
        const float* __restrict__ Wq, const float* __restrict__ Wk,
        const float* __restrict__ Wv, const float* __restrict__ Wo,
        float* __restrict__ s_shift, unsigned short* __restrict__ tln,
        unsigned short* __restrict__ wt, float* __restrict__ out,
        unsigned* __restrict__ ctr) {
    __shared__ float smem[32 * 33];
    int bid = blockIdx.x, tid = threadIdx.x;
    if (bid < K1_LN) {
        int r = bid, seg = r & (NSEG - 1);
        float vals[3]; float local = 0.f;
        #pragma unroll
        for (int i = 0; i < 3; ++i) {
            int c = tid + i * 256;
            float v = x[(size_t)r * PP * CC + c];
            if (seg > 0) v += w1[c] * x[(size_t)(r - 1) * PP * CC + c];
            vals[i] = v; local += v;
        }
        smem[tid] = local; __syncthreads();
        for (int off = 128; off > 0; off >>= 1) {
            if (tid < off) smem[tid] += smem[tid + off];
            __syncthreads();
        }
        float mu = smem[0] * (1.0f / CC); __syncthreads();
        float lv = 0.f;
        #pragma unroll
        for (int i = 0; i < 3; ++i) { float d = vals[i] - mu; lv += d * d; }
        smem[tid] = lv; __syncthreads();
        for (int off = 128; off > 0; off >>= 1) {
            if (tid < off) smem[tid] += smem[tid + off];
            __syncthreads();
        }
        float rstd = rsqrtf(smem[0] * (1.0f / CC) + LN_EPS);
        #pragma unroll
        for (int i = 0; i < 3; ++i) {
            int c = tid + i * 256;
            s_shift[(size_t)r * CC + c] = vals[i];
            tln[(size_t)r * CC + c] = f2bf((vals[i] - mu) * rstd * g[c] + bln[c]);
        }
    } else if (bid < K1_LN + K1_CVT) {
        int bi = bid - K1_LN;
        #pragma unroll
        for (int rep = 0; rep < 3; ++rep) {
            int idx = bi + rep * K1_CVT;
            int mat = idx / 576, tile = idx % 576;
            int tr = tile / 24, tc = tile % 24;
            const float* W = mat == 0 ? Wq : mat == 1 ? Wk : mat == 2 ? Wv : Wo;
            int lr = tid >> 3, lc = (tid & 7) * 4;
            float4 v = *(const float4*)(W + (size_t)(tr * 32 + lr) * CC + tc * 32 + lc);
            smem[lr * 33 + lc + 0] = v.x; smem[lr * 33 + lc + 1] = v.y;
            smem[lr * 33 + lc + 2] = v.z; smem[lr * 33 + lc + 3] = v.w;
            __syncthreads();
            int ln_ = tid >> 3, kc = (tid & 7) * 4;
            us4 o;
            #pragma unroll
            for (int j = 0; j < 4; ++j) o[j] = f2bf(smem[(kc + j) * 33 + ln_]);
            *(us4*)(wt + (size_t)mat * CC * CC + (size_t)(tc * 32 + ln_) * CC + tr * 32 + kc) = o;
            __syncthreads();
        }
    }
    copy_dyn(x, out, ctr, B1, L1);
}

// ================= K2: QKV MFMA GEMM (288) | copy (1024) =================
constexpr int K2_GEMM = 288, K2_CPY = 1024;
__global__ __launch_bounds__(256) void k2(const unsigned short* __restrict__ tln,
        const unsigned short* __restrict__ wt,
        const float* __restrict__ bq, const float* __restrict__ bk, const float* __restrict__ bv,
        float* __restrict__ qkv,
        const float* __restrict__ x, float* __restrict__ out,
        unsigned* __restrict__ ctr) {
    int bid = blockIdx.x;
    if (bid < K2_GEMM) {
        int z = bid / 96, rem = bid % 96;
        int by = rem / 12, bx = rem % 12;
        const unsigned short* Bt = wt + (size_t)z * CC * CC;
        const float* bias = z == 0 ? bq : (z == 1 ? bk : bv);
        float* outp = qkv + (size_t)z * MN;
        gemm_tile<false>(tln, Bt, bias, nullptr, outp, by, bx, CC);
    }
    copy_dyn(x, out, ctr, B2, L2);
}

// ================= K3: attention (384) | copy (1024) =================
constexpr int K3_ATT = 32 * NH, K3_CPY = 1024;
__global__ __launch_bounds__(256) void k3(const float* __restrict__ qkv,
        unsigned short* __restrict__ ctxb,
        const float* __restrict__ x, float* __restrict__ out,
        unsigned* __restrict__ ctr) {
    int bid = blockIdx.x, tid = threadIdx.x;
    if (bid < K3_ATT) {
        const float* q = qkv;
        const float* k = qkv + MN;
        const float* v = qkv + 2 * MN;
        int bb = bid / NH, h = bid % NH;
        __shared__ float qs[16][HD], ks[16][HD], vs[16][HD];
        __shared__ float sc[16][17];
        __shared__ float rsum[16];
        for (int i = tid; i < 16 * HD; i += 256) {
            int t = i >> 6, d = i & 63;
            size_t gidx = (size_t)(bb * NSEG + t) * CC + h * HD + d;
            qs[t][d] = q[gidx]; ks[t][d] = k[gidx]; vs[t][d] = v[gidx];
        }
        __syncthreads();
        {
            int t = tid >> 4, s = tid & 15;
            float acc = 0.f;
            #pragma unroll
            for (int d = 0; d < HD; ++d) acc += qs[t][d] * ks[s][d];
            sc[t][s] = acc * 0.125f;
        }
        __syncthreads();
        if (tid < 16) {
            float m = -1e30f;
            #pragma unroll
            for (int s = 0; s < 16; ++s) m = fmaxf(m, sc[tid][s]);
            float sum = 0.f;
            #pragma unroll
            for (int s = 0; s < 16; ++s) { float e = __expf(sc[tid][s] - m); sc[tid][s] = e; sum += e; }
            rsum[tid] = sum;
        }
        __syncthreads();
        for (int i = tid; i < 16 * HD; i += 256) {
            int t = i >> 6, d = i & 63;
            float acc = 0.f;
            #pragma unroll
            for (int s = 0; s < 16; ++s) acc += sc[t][s] * vs[s][d];
            ctxb[(size_t)(bb * NSEG + t) * CC + h * HD + d] = f2bf(acc / rsum[t]);
        }
    }
    copy_dyn(x, out, ctr, B3, L3);
}

// ================= K4: O-proj GEMM + residual into out[p=0] (96) | copy (1024) =================
constexpr int K4_GEMM = 96, K4_CPY = 1024;
__global__ __launch_bounds__(256) void k4(const unsigned short* __restrict__ ctxb,
        const unsigned short* __restrict__ wto,
        const float* __restrict__ bo, const float* __restrict__ s_shift,
        float* __restrict__ out, const float* __restrict__ x,
        unsigned* __restrict__ ctr) {
    int bid = blockIdx.x;
    if (bid < K4_GEMM) {
        int by = bid / 12, bx = bid % 12;
        gemm_tile<true>(ctxb, wto, bo, s_shift, out, by, bx, (size_t)PP * CC);
    }
    copy_dyn(x, out, ctr, B4, L4);
}

extern "C" void kernel_launch(void* const* d_in, const int* in_sizes, int n_in,
                              void* d_out, int out_size, void* d_ws, size_t ws_size,
                              hipStream_t stream) {
    const float* x    = (const float*)d_in[0];
    const float* w1   = (const float*)d_in[1];
    const float* ln_g = (const float*)d_in[2];
    const float* ln_b = (const float*)d_in[3];
    const float* Wq   = (const float*)d_in[4];
    const float* bq   = (const float*)d_in[5];
    const float* Wk   = (const float*)d_in[6];
    const float* bk   = (const float*)d_in[7];
    const float* Wv   = (const float*)d_in[8];
    const float* bv   = (const float*)d_in[9];
    const float* Wo   = (const float*)d_in[10];
    const float* bo   = (const float*)d_in[11];
    float* out = (float*)d_out;

    unsigned* ctrs = (unsigned*)d_ws;                          // 4 counters (256B region)
    float* fbase   = (float*)d_ws + 64;
    float* s_shift = fbase;                                    // MN f32
    float* qkv     = s_shift + MN;                             // 3*MN f32
    unsigned short* tln  = (unsigned short*)(qkv + 3 * MN);    // MN bf16
    unsigned short* ctxb = tln + MN;                           // MN bf16
    unsigned short* wt   = ctxb + MN;                          // 4*CC*CC bf16

    (void)hipMemsetAsync(d_ws, 0, 256, stream);   // zero the 4 chunk counters each launch

    k1<<<K1_LN + K1_CVT + K1_CPY, 256, 0, stream>>>(x, w1, ln_g, ln_b, Wq, Wk, Wv, Wo,
                                                    s_shift, tln, wt, out, ctrs + 0);
    k2<<<K2_GEMM + K2_CPY, 256, 0, stream>>>(tln, wt, bq, bk, bv, qkv, x, out, ctrs + 1);
    k3<<<K3_ATT + K3_CPY, 256, 0, stream>>>(qkv, ctxb, x, out, ctrs + 2);
    k4<<<K4_GEMM + K4_CPY, 256, 0, stream>>>(ctxb, wt + (size_t)3 * CC * CC, bo, s_shift,
                                             out, x, ctrs + 3);
}

// Round 7
// 248.284 us; speedup vs baseline: 4.6128x; 4.6128x over previous
//
#include <hip/hip_runtime.h>
#include <math.h>

typedef __attribute__((ext_vector_type(8))) short short8;
typedef __attribute__((ext_vector_type(4))) float f32x4;
typedef __attribute__((ext_vector_type(4))) unsigned short us4;

constexpr int NSEG = 16;
constexpr int CC   = 768;
constexpr int PP   = 197;
constexpr int NH   = 12;
constexpr int HD   = 64;
constexpr int NT   = 512;
constexpr int MN   = NT * CC;
constexpr float LN_EPS = 1e-5f;

// pass-through copy geometry, float4 units (p>=1 rows of every token)
constexpr unsigned CPT  = 196 * CC / 4;          // 37632
constexpr unsigned ROW4 = CC / 4;                // 192
constexpr unsigned W4TOT = (unsigned)NT * CPT;   // 19267584

// static uniform copy quotas: 3 kernels x 2048 blocks
constexpr unsigned Q1 = 2944, S1 = 0;
constexpr unsigned Q2 = 3248, S2 = S1 + 2048u * Q1;   // 6029312
constexpr unsigned Q3 = 3216, S3 = S2 + 2048u * Q2;   // 12681216; S3+2048*Q3 == W4TOT

__device__ inline unsigned short f2bf(float f) {
    unsigned u = __float_as_uint(f);
    u += 0x7fffu + ((u >> 16) & 1u);
    return (unsigned short)(u >> 16);
}
__device__ inline float bf2f(short v) {
    return __uint_as_float((unsigned)(unsigned short)v << 16);
}
__device__ inline unsigned cidx(unsigned i) {
    unsigned t = i / CPT;                 // magic-mul div
    return i + t * ROW4 + ROW4;
}

// static per-block contiguous-quota copy
__device__ inline void copy_blk(const float* __restrict__ xf, float* __restrict__ of,
                                unsigned rbeg, unsigned rend, int tid) {
    const f32x4* __restrict__ x4 = (const f32x4*)xf;
    f32x4* __restrict__ o4 = (f32x4*)of;
    for (unsigned i = rbeg + tid; i < rend; i += 256) {
        unsigned a = cidx(i);
        o4[a] = x4[a];
    }
}

// ================= K1: LN (512) | weight cvt 4x (576) | copy-only (960) — 2048 blocks =================
__global__ __launch_bounds__(256, 8) void k1(const float* __restrict__ x, const float* __restrict__ w1,
        const float* __restrict__ g, const float* __restrict__ bln,
        const float* __restrict__ Wq, const float* __restrict__ Wk,
        const float* __restrict__ Wv, const float* __restrict__ Wo,
        float* __restrict__ s_shift, unsigned short* __restrict__ tln,
        unsigned short* __restrict__ wt, float* __restrict__ out) {
    __shared__ float smem[32 * 33];
    int bid = blockIdx.x, tid = threadIdx.x;
    if (bid < NT) {
        int r = bid, seg = r & (NSEG - 1);
        float vals[3]; float local = 0.f;
        #pragma unroll
        for (int i = 0; i < 3; ++i) {
            int c = tid + i * 256;
            float v = x[(size_t)r * PP * CC + c];
            if (seg > 0) v += w1[c] * x[(size_t)(r - 1) * PP * CC + c];
            vals[i] = v; local += v;
        }
        smem[tid] = local; __syncthreads();
        for (int off = 128; off > 0; off >>= 1) {
            if (tid < off) smem[tid] += smem[tid + off];
            __syncthreads();
        }
        float mu = smem[0] * (1.0f / CC); __syncthreads();
        float lv = 0.f;
        #pragma unroll
        for (int i = 0; i < 3; ++i) { float d = vals[i] - mu; lv += d * d; }
        smem[tid] = lv; __syncthreads();
        for (int off = 128; off > 0; off >>= 1) {
            if (tid < off) smem[tid] += smem[tid + off];
            __syncthreads();
        }
        float rstd = rsqrtf(smem[0] * (1.0f / CC) + LN_EPS);
        #pragma unroll
        for (int i = 0; i < 3; ++i) {
            int c = tid + i * 256;
            s_shift[(size_t)r * CC + c] = vals[i];
            tln[(size_t)r * CC + c] = f2bf((vals[i] - mu) * rstd * g[c] + bln[c]);
        }
    } else if (bid < NT + 576) {
        int bi = bid - NT;              // one 32x32 tile from each of the 4 matrices
        int tr = bi / 24, tc = bi % 24;
        #pragma unroll
        for (int rep = 0; rep < 4; ++rep) {
            const float* W = rep == 0 ? Wq : rep == 1 ? Wk : rep == 2 ? Wv : Wo;
            int lr = tid >> 3, lc = (tid & 7) * 4;
            float4 v = *(const float4*)(W + (size_t)(tr * 32 + lr) * CC + tc * 32 + lc);
            smem[lr * 33 + lc + 0] = v.x; smem[lr * 33 + lc + 1] = v.y;
            smem[lr * 33 + lc + 2] = v.z; smem[lr * 33 + lc + 3] = v.w;
            __syncthreads();
            int ln_ = tid >> 3, kc = (tid & 7) * 4;
            us4 o;
            #pragma unroll
            for (int j = 0; j < 4; ++j) o[j] = f2bf(smem[(kc + j) * 33 + ln_]);
            *(us4*)(wt + (size_t)rep * CC * CC + (size_t)(tc * 32 + ln_) * CC + tr * 32 + kc) = o;
            __syncthreads();
        }
    }
    copy_blk(x, out, S1 + (unsigned)bid * Q1, S1 + (unsigned)(bid + 1) * Q1, tid);
}

// ================= K2: QKV MFMA GEMM -> bf16 (288) | copy (1760) — 2048 blocks =================
__global__ __launch_bounds__(256, 4) void k2(const unsigned short* __restrict__ tln,
        const unsigned short* __restrict__ wt,
        const float* __restrict__ bq, const float* __restrict__ bk, const float* __restrict__ bv,
        unsigned short* __restrict__ qkvb,
        const float* __restrict__ x, float* __restrict__ out) {
    int bid = blockIdx.x, tid = threadIdx.x;
    if (bid < 288) {
        int z = bid / 96, rem = bid % 96;
        int by = rem / 12, bx = rem % 12;
        const unsigned short* Bt = wt + (size_t)z * CC * CC;
        const float* bias = z == 0 ? bq : (z == 1 ? bk : bv);
        unsigned short* outp = qkvb + (size_t)z * MN;
        int lane = tid & 63, wv = tid >> 6;
        int wr = wv >> 1, wc = wv & 1;
        int l15 = lane & 15, lh = lane >> 4;
        int m0 = by * 64 + wr * 32;
        int n0 = bx * 64 + wc * 32;
        f32x4 acc[2][2] = {};
        const unsigned short* Ar0 = tln + (size_t)(m0 + l15) * CC + lh * 8;
        const unsigned short* Ar1 = Ar0 + 16 * CC;
        const unsigned short* Br0 = Bt + (size_t)(n0 + l15) * CC + lh * 8;
        const unsigned short* Br1 = Br0 + 16 * CC;
        #pragma unroll 4
        for (int k0 = 0; k0 < CC; k0 += 32) {
            short8 a0 = *(const short8*)(Ar0 + k0);
            short8 a1 = *(const short8*)(Ar1 + k0);
            short8 b0 = *(const short8*)(Br0 + k0);
            short8 b1 = *(const short8*)(Br1 + k0);
            acc[0][0] = __builtin_amdgcn_mfma_f32_16x16x32_bf16(a0, b0, acc[0][0], 0, 0, 0);
            acc[0][1] = __builtin_amdgcn_mfma_f32_16x16x32_bf16(a0, b1, acc[0][1], 0, 0, 0);
            acc[1][0] = __builtin_amdgcn_mfma_f32_16x16x32_bf16(a1, b0, acc[1][0], 0, 0, 0);
            acc[1][1] = __builtin_amdgcn_mfma_f32_16x16x32_bf16(a1, b1, acc[1][1], 0, 0, 0);
        }
        #pragma unroll
        for (int mf = 0; mf < 2; ++mf)
            #pragma unroll
            for (int nf = 0; nf < 2; ++nf)
                #pragma unroll
                for (int r = 0; r < 4; ++r) {
                    int row = m0 + mf * 16 + lh * 4 + r;
                    int col = n0 + nf * 16 + l15;
                    outp[(size_t)row * CC + col] = f2bf(acc[mf][nf][r] + bias[col]);
                }
    }
    copy_blk(x, out, S2 + (unsigned)bid * Q2, S2 + (unsigned)(bid + 1) * Q2, tid);
}

// ================= K3: fused attn + O-proj per batch (32) | copy (2016) — 2048 blocks =================
__global__ __launch_bounds__(256, 4) void k3(const unsigned short* __restrict__ qkvb,
        const unsigned short* __restrict__ wto,
        const float* __restrict__ bo, const float* __restrict__ s_shift,
        unsigned short* __restrict__ ctxb,
        float* __restrict__ out, const float* __restrict__ x) {
    __shared__ float Plds[4][16][17];
    int bid = blockIdx.x, tid = threadIdx.x;
    if (bid < 32) {
        int bb = bid;
        int w = tid >> 6, lane = tid & 63;
        int t = lane & 15, sg = lane >> 4;
        const unsigned short* qb = qkvb;
        const unsigned short* kb = qkvb + MN;
        const unsigned short* vb = qkvb + 2 * MN;
        for (int r = 0; r < 3; ++r) {
            int h = r * 4 + w;                       // wave w -> head h
            // ---- scores: lane computes S[t][sg*4+j], j=0..3 ----
            const unsigned short* qrow = qb + (size_t)(bb * NSEG + t) * CC + h * HD;
            const unsigned short* kbase = kb + (size_t)(bb * NSEG) * CC + h * HD;
            float sc[4] = {0.f, 0.f, 0.f, 0.f};
            int s0 = sg * 4;
            for (int c8 = 0; c8 < 8; ++c8) {
                short8 q8 = *(const short8*)(qrow + c8 * 8);
                #pragma unroll
                for (int j = 0; j < 4; ++j) {
                    short8 k8 = *(const short8*)(kbase + (size_t)(s0 + j) * CC + c8 * 8);
                    #pragma unroll
                    for (int e = 0; e < 8; ++e) sc[j] += bf2f(q8[e]) * bf2f(k8[e]);
                }
            }
            #pragma unroll
            for (int j = 0; j < 4; ++j) sc[j] *= 0.125f;
            // ---- softmax over s (16 values spread over 4 lanes x 4 regs) ----
            float m = fmaxf(fmaxf(sc[0], sc[1]), fmaxf(sc[2], sc[3]));
            m = fmaxf(m, __shfl_xor(m, 16));
            m = fmaxf(m, __shfl_xor(m, 32));
            float e4[4], ssum = 0.f;
            #pragma unroll
            for (int j = 0; j < 4; ++j) { e4[j] = __expf(sc[j] - m); ssum += e4[j]; }
            ssum += __shfl_xor(ssum, 16);
            ssum += __shfl_xor(ssum, 32);
            float inv = 1.f / ssum;
            #pragma unroll
            for (int j = 0; j < 4; ++j) Plds[w][t][s0 + j] = e4[j] * inv;
            // ---- PV: lane computes ctx[t][dg*16 .. +16] ----
            int dg = sg;
            const unsigned short* vbase = vb + (size_t)(bb * NSEG) * CC + h * HD + dg * 16;
            float o[16];
            #pragma unroll
            for (int e = 0; e < 16; ++e) o[e] = 0.f;
            for (int s = 0; s < 16; ++s) {
                float p = Plds[w][t][s];
                short8 va = *(const short8*)(vbase + (size_t)s * CC);
                short8 vbk = *(const short8*)(vbase + (size_t)s * CC + 8);
                #pragma unroll
                for (int e = 0; e < 8; ++e) { o[e] += p * bf2f(va[e]); o[8 + e] += p * bf2f(vbk[e]); }
            }
            unsigned short* cdst = ctxb + (size_t)(bb * NSEG + t) * CC + h * HD + dg * 16;
            #pragma unroll
            for (int e4i = 0; e4i < 4; ++e4i) {
                us4 ob;
                #pragma unroll
                for (int j = 0; j < 4; ++j) ob[j] = f2bf(o[e4i * 4 + j]);
                *(us4*)(cdst + e4i * 4) = ob;
            }
        }
        __threadfence_block();
        __syncthreads();
        // ---- O-proj: 48 n-tiles over 4 waves, A = ctxb rows (bf16), B = wto [n][k] ----
        int l15 = lane & 15, lh = lane >> 4;
        const unsigned short* Arow = ctxb + (size_t)(bb * NSEG + l15) * CC + lh * 8;
        for (int ti = 0; ti < 12; ++ti) {
            int n0 = (w + ti * 4) * 16;
            const unsigned short* Brow = wto + (size_t)(n0 + l15) * CC + lh * 8;
            f32x4 acc = {0.f, 0.f, 0.f, 0.f};
            #pragma unroll 4
            for (int k0 = 0; k0 < CC; k0 += 32) {
                short8 a = *(const short8*)(Arow + k0);
                short8 b = *(const short8*)(Brow + k0);
                acc = __builtin_amdgcn_mfma_f32_16x16x32_bf16(a, b, acc, 0, 0, 0);
            }
            #pragma unroll
            for (int rr = 0; rr < 4; ++rr) {
                int row = lh * 4 + rr;
                int col = n0 + l15;
                float v = acc[rr] + bo[col] + s_shift[(size_t)(bb * NSEG + row) * CC + col];
                out[(size_t)(bb * NSEG + row) * (size_t)(PP * CC) + col] = v;
            }
        }
    }
    copy_blk(x, out, S3 + (unsigned)bid * Q3, S3 + (unsigned)(bid + 1) * Q3, tid);
}

extern "C" void kernel_launch(void* const* d_in, const int* in_sizes, int n_in,
                              void* d_out, int out_size, void* d_ws, size_t ws_size,
                              hipStream_t stream) {
    const float* x    = (const float*)d_in[0];
    const float* w1   = (const float*)d_in[1];
    const float* ln_g = (const float*)d_in[2];
    const float* ln_b = (const float*)d_in[3];
    const float* Wq   = (const float*)d_in[4];
    const float* bq   = (const float*)d_in[5];
    const float* Wk   = (const float*)d_in[6];
    const float* bk   = (const float*)d_in[7];
    const float* Wv   = (const float*)d_in[8];
    const float* bv   = (const float*)d_in[9];
    const float* Wo   = (const float*)d_in[10];
    const float* bo   = (const float*)d_in[11];
    float* out = (float*)d_out;

    float* s_shift = (float*)d_ws;                            // MN f32
    unsigned short* tln  = (unsigned short*)(s_shift + MN);   // MN bf16
    unsigned short* qkvb = tln + MN;                          // 3*MN bf16
    unsigned short* ctxb = qkvb + 3 * (size_t)MN;             // MN bf16
    unsigned short* wt   = ctxb + MN;                         // 4*CC*CC bf16

    k1<<<2048, 256, 0, stream>>>(x, w1, ln_g, ln_b, Wq, Wk, Wv, Wo, s_shift, tln, wt, out);
    k2<<<2048, 256, 0, stream>>>(tln, wt, bq, bk, bv, qkvb, x, out);
    k3<<<2048, 256, 0, stream>>>(qkvb, wt + (size_t)3 * CC * CC, bo, s_shift, ctxb, out, x);
}

// Round 8
// 208.681 us; speedup vs baseline: 5.4882x; 1.1898x over previous
//
#include <hip/hip_runtime.h>
#include <math.h>

typedef __attribute__((ext_vector_type(8))) short short8;
typedef __attribute__((ext_vector_type(4))) float f32x4;
typedef __attribute__((ext_vector_type(4))) unsigned short us4;

constexpr int NSEG = 16;
constexpr int CC   = 768;
constexpr int PP   = 197;
constexpr int NH   = 12;
constexpr int HD   = 64;
constexpr int NT   = 512;
constexpr int MN   = NT * CC;
constexpr float LN_EPS = 1e-5f;

// pass-through copy geometry, float4 units (p>=1 rows of every token)
constexpr unsigned CPT  = 196 * CC / 4;          // 37632
constexpr unsigned ROW4 = CC / 4;                // 192
constexpr unsigned W4TOT = (unsigned)NT * CPT;   // 19267584

// copy-block counts and slice lengths per kernel
constexpr unsigned NC1 = 960,  NC2 = 1760, NC3 = 2016;
constexpr unsigned L1 = 3932160u;                 // 960*256*16
constexpr unsigned L2 = 7208960u;                 // 1760*256*16
constexpr unsigned L3 = W4TOT - L1 - L2;          // 8126464
constexpr unsigned B1 = 0, B2 = L1, B3 = L1 + L2;

__device__ inline unsigned short f2bf(float f) {
    unsigned u = __float_as_uint(f);
    u += 0x7fffu + ((u >> 16) & 1u);
    return (unsigned short)(u >> 16);
}
__device__ inline float bf2f(short v) {
    return __uint_as_float((unsigned)(unsigned short)v << 16);
}
__device__ inline unsigned cidx(unsigned i) {
    unsigned t = i / CPT;                 // magic-mul div
    return i + t * ROW4 + ROW4;
}

// device-strided dense-window copy: all copy threads march one contiguous front
__device__ inline void copy_strided(const float* __restrict__ xf, float* __restrict__ of,
                                    unsigned base, unsigned len,
                                    unsigned ct, unsigned nth) {
    const f32x4* __restrict__ x4 = (const f32x4*)xf;
    f32x4* __restrict__ o4 = (f32x4*)of;
    for (unsigned i = ct; i < len; i += nth) {
        unsigned a = cidx(base + i);
        o4[a] = x4[a];
    }
}

// ================= K1: LN (512) | weight cvt 4x (576) | copy (960) — 2048 blocks =================
__global__ __launch_bounds__(256, 8) void k1(const float* __restrict__ x, const float* __restrict__ w1,
        const float* __restrict__ g, const float* __restrict__ bln,
        const float* __restrict__ Wq, const float* __restrict__ Wk,
        const float* __restrict__ Wv, const float* __restrict__ Wo,
        float* __restrict__ s_shift, unsigned short* __restrict__ tln,
        unsigned short* __restrict__ wt, float* __restrict__ out) {
    __shared__ float smem[32 * 33];
    int bid = blockIdx.x, tid = threadIdx.x;
    if (bid < NT) {
        int r = bid, seg = r & (NSEG - 1);
        float vals[3]; float local = 0.f;
        #pragma unroll
        for (int i = 0; i < 3; ++i) {
            int c = tid + i * 256;
            float v = x[(size_t)r * PP * CC + c];
            if (seg > 0) v += w1[c] * x[(size_t)(r - 1) * PP * CC + c];
            vals[i] = v; local += v;
        }
        smem[tid] = local; __syncthreads();
        for (int off = 128; off > 0; off >>= 1) {
            if (tid < off) smem[tid] += smem[tid + off];
            __syncthreads();
        }
        float mu = smem[0] * (1.0f / CC); __syncthreads();
        float lv = 0.f;
        #pragma unroll
        for (int i = 0; i < 3; ++i) { float d = vals[i] - mu; lv += d * d; }
        smem[tid] = lv; __syncthreads();
        for (int off = 128; off > 0; off >>= 1) {
            if (tid < off) smem[tid] += smem[tid + off];
            __syncthreads();
        }
        float rstd = rsqrtf(smem[0] * (1.0f / CC) + LN_EPS);
        #pragma unroll
        for (int i = 0; i < 3; ++i) {
            int c = tid + i * 256;
            s_shift[(size_t)r * CC + c] = vals[i];
            tln[(size_t)r * CC + c] = f2bf((vals[i] - mu) * rstd * g[c] + bln[c]);
        }
    } else if (bid < NT + 576) {
        int bi = bid - NT;              // one 32x32 tile from each of the 4 matrices
        int tr = bi / 24, tc = bi % 24;
        #pragma unroll
        for (int rep = 0; rep < 4; ++rep) {
            const float* W = rep == 0 ? Wq : rep == 1 ? Wk : rep == 2 ? Wv : Wo;
            int lr = tid >> 3, lc = (tid & 7) * 4;
            float4 v = *(const float4*)(W + (size_t)(tr * 32 + lr) * CC + tc * 32 + lc);
            smem[lr * 33 + lc + 0] = v.x; smem[lr * 33 + lc + 1] = v.y;
            smem[lr * 33 + lc + 2] = v.z; smem[lr * 33 + lc + 3] = v.w;
            __syncthreads();
            int ln_ = tid >> 3, kc = (tid & 7) * 4;
            us4 o;
            #pragma unroll
            for (int j = 0; j < 4; ++j) o[j] = f2bf(smem[(kc + j) * 33 + ln_]);
            *(us4*)(wt + (size_t)rep * CC * CC + (size_t)(tc * 32 + ln_) * CC + tr * 32 + kc) = o;
            __syncthreads();
        }
    } else {
        unsigned ct = (unsigned)(bid - (NT + 576)) * 256 + tid;
        copy_strided(x, out, B1, L1, ct, NC1 * 256);
    }
}

// ================= K2: QKV MFMA GEMM -> bf16 (288) | copy (1760) — 2048 blocks =================
__global__ __launch_bounds__(256) void k2(const unsigned short* __restrict__ tln,
        const unsigned short* __restrict__ wt,
        const float* __restrict__ bq, const float* __restrict__ bk, const float* __restrict__ bv,
        unsigned short* __restrict__ qkvb,
        const float* __restrict__ x, float* __restrict__ out) {
    int bid = blockIdx.x, tid = threadIdx.x;
    if (bid < 288) {
        int z = bid / 96, rem = bid % 96;
        int by = rem / 12, bx = rem % 12;
        const unsigned short* Bt = wt + (size_t)z * CC * CC;
        const float* bias = z == 0 ? bq : (z == 1 ? bk : bv);
        unsigned short* outp = qkvb + (size_t)z * MN;
        int lane = tid & 63, wv = tid >> 6;
        int wr = wv >> 1, wc = wv & 1;
        int l15 = lane & 15, lh = lane >> 4;
        int m0 = by * 64 + wr * 32;
        int n0 = bx * 64 + wc * 32;
        f32x4 acc[2][2] = {};
        const unsigned short* Ar0 = tln + (size_t)(m0 + l15) * CC + lh * 8;
        const unsigned short* Ar1 = Ar0 + 16 * CC;
        const unsigned short* Br0 = Bt + (size_t)(n0 + l15) * CC + lh * 8;
        const unsigned short* Br1 = Br0 + 16 * CC;
        #pragma unroll 4
        for (int k0 = 0; k0 < CC; k0 += 32) {
            short8 a0 = *(const short8*)(Ar0 + k0);
            short8 a1 = *(const short8*)(Ar1 + k0);
            short8 b0 = *(const short8*)(Br0 + k0);
            short8 b1 = *(const short8*)(Br1 + k0);
            acc[0][0] = __builtin_amdgcn_mfma_f32_16x16x32_bf16(a0, b0, acc[0][0], 0, 0, 0);
            acc[0][1] = __builtin_amdgcn_mfma_f32_16x16x32_bf16(a0, b1, acc[0][1], 0, 0, 0);
            acc[1][0] = __builtin_amdgcn_mfma_f32_16x16x32_bf16(a1, b0, acc[1][0], 0, 0, 0);
            acc[1][1] = __builtin_amdgcn_mfma_f32_16x16x32_bf16(a1, b1, acc[1][1], 0, 0, 0);
        }
        #pragma unroll
        for (int mf = 0; mf < 2; ++mf)
            #pragma unroll
            for (int nf = 0; nf < 2; ++nf)
                #pragma unroll
                for (int r = 0; r < 4; ++r) {
                    int row = m0 + mf * 16 + lh * 4 + r;
                    int col = n0 + nf * 16 + l15;
                    outp[(size_t)row * CC + col] = f2bf(acc[mf][nf][r] + bias[col]);
                }
    } else {
        unsigned ct = (unsigned)(bid - 288) * 256 + tid;
        copy_strided(x, out, B2, L2, ct, NC2 * 256);
    }
}

// ================= K3: fused attn + O-proj per batch (32) | copy (2016) — 2048 blocks =================
__global__ __launch_bounds__(256) void k3(const unsigned short* __restrict__ qkvb,
        const unsigned short* __restrict__ wto,
        const float* __restrict__ bo, const float* __restrict__ s_shift,
        unsigned short* __restrict__ ctxb,
        float* __restrict__ out, const float* __restrict__ x) {
    __shared__ float Plds[4][16][17];
    int bid = blockIdx.x, tid = threadIdx.x;
    if (bid < 32) {
        int bb = bid;
        int w = tid >> 6, lane = tid & 63;
        int t = lane & 15, sg = lane >> 4;
        const unsigned short* qb = qkvb;
        const unsigned short* kb = qkvb + MN;
        const unsigned short* vb = qkvb + 2 * MN;
        for (int r = 0; r < 3; ++r) {
            int h = r * 4 + w;                       // wave w -> head h
            const unsigned short* qrow = qb + (size_t)(bb * NSEG + t) * CC + h * HD;
            const unsigned short* kbase = kb + (size_t)(bb * NSEG) * CC + h * HD;
            float sc[4] = {0.f, 0.f, 0.f, 0.f};
            int s0 = sg * 4;
            for (int c8 = 0; c8 < 8; ++c8) {
                short8 q8 = *(const short8*)(qrow + c8 * 8);
                #pragma unroll
                for (int j = 0; j < 4; ++j) {
                    short8 k8 = *(const short8*)(kbase + (size_t)(s0 + j) * CC + c8 * 8);
                    #pragma unroll
                    for (int e = 0; e < 8; ++e) sc[j] += bf2f(q8[e]) * bf2f(k8[e]);
                }
            }
            #pragma unroll
            for (int j = 0; j < 4; ++j) sc[j] *= 0.125f;
            float m = fmaxf(fmaxf(sc[0], sc[1]), fmaxf(sc[2], sc[3]));
            m = fmaxf(m, __shfl_xor(m, 16));
            m = fmaxf(m, __shfl_xor(m, 32));
            float e4[4], ssum = 0.f;
            #pragma unroll
            for (int j = 0; j < 4; ++j) { e4[j] = __expf(sc[j] - m); ssum += e4[j]; }
            ssum += __shfl_xor(ssum, 16);
            ssum += __shfl_xor(ssum, 32);
            float inv = 1.f / ssum;
            #pragma unroll
            for (int j = 0; j < 4; ++j) Plds[w][t][s0 + j] = e4[j] * inv;
            int dg = sg;
            const unsigned short* vbase = vb + (size_t)(bb * NSEG) * CC + h * HD + dg * 16;
            float o[16];
            #pragma unroll
            for (int e = 0; e < 16; ++e) o[e] = 0.f;
            for (int s = 0; s < 16; ++s) {
                float p = Plds[w][t][s];
                short8 va = *(const short8*)(vbase + (size_t)s * CC);
                short8 vbk = *(const short8*)(vbase + (size_t)s * CC + 8);
                #pragma unroll
                for (int e = 0; e < 8; ++e) { o[e] += p * bf2f(va[e]); o[8 + e] += p * bf2f(vbk[e]); }
            }
            unsigned short* cdst = ctxb + (size_t)(bb * NSEG + t) * CC + h * HD + dg * 16;
            #pragma unroll
            for (int e4i = 0; e4i < 4; ++e4i) {
                us4 ob;
                #pragma unroll
                for (int j = 0; j < 4; ++j) ob[j] = f2bf(o[e4i * 4 + j]);
                *(us4*)(cdst + e4i * 4) = ob;
            }
        }
        __threadfence_block();
        __syncthreads();
        // O-proj: 48 n-tiles over 4 waves, A = ctxb rows (bf16), B = wto [n][k]
        int l15 = lane & 15, lh = lane >> 4;
        const unsigned short* Arow = ctxb + (size_t)(bb * NSEG + l15) * CC + lh * 8;
        for (int ti = 0; ti < 12; ++ti) {
            int n0 = (w + ti * 4) * 16;
            const unsigned short* Brow = wto + (size_t)(n0 + l15) * CC + lh * 8;
            f32x4 acc = {0.f, 0.f, 0.f, 0.f};
            #pragma unroll 4
            for (int k0 = 0; k0 < CC; k0 += 32) {
                short8 a = *(const short8*)(Arow + k0);
                short8 b = *(const short8*)(Brow + k0);
                acc = __builtin_amdgcn_mfma_f32_16x16x32_bf16(a, b, acc, 0, 0, 0);
            }
            #pragma unroll
            for (int rr = 0; rr < 4; ++rr) {
                int row = lh * 4 + rr;
                int col = n0 + l15;
                float v = acc[rr] + bo[col] + s_shift[(size_t)(bb * NSEG + row) * CC + col];
                out[(size_t)(bb * NSEG + row) * (size_t)(PP * CC) + col] = v;
            }
        }
    } else {
        unsigned ct = (unsigned)(bid - 32) * 256 + tid;
        copy_strided(x, out, B3, L3, ct, NC3 * 256);
    }
}

extern "C" void kernel_launch(void* const* d_in, const int* in_sizes, int n_in,
                              void* d_out, int out_size, void* d_ws, size_t ws_size,
                              hipStream_t stream) {
    const float* x    = (const float*)d_in[0];
    const float* w1   = (const float*)d_in[1];
    const float* ln_g = (const float*)d_in[2];
    const float* ln_b = (const float*)d_in[3];
    const float* Wq   = (const float*)d_in[4];
    const float* bq   = (const float*)d_in[5];
    const float* Wk   = (const float*)d_in[6];
    const float* bk   = (const float*)d_in[7];
    const float* Wv   = (const float*)d_in[8];
    const float* bv   = (const float*)d_in[9];
    const float* Wo   = (const float*)d_in[10];
    const float* bo   = (const float*)d_in[11];
    float* out = (float*)d_out;

    float* s_shift = (float*)d_ws;                            // MN f32
    unsigned short* tln  = (unsigned short*)(s_shift + MN);   // MN bf16
    unsigned short* qkvb = tln + MN;                          // 3*MN bf16
    unsigned short* ctxb = qkvb + 3 * (size_t)MN;             // MN bf16
    unsigned short* wt   = ctxb + MN;                         // 4*CC*CC bf16

    k1<<<2048, 256, 0, stream>>>(x, w1, ln_g, ln_b, Wq, Wk, Wv, Wo, s_shift, tln, wt, out);
    k2<<<2048, 256, 0, stream>>>(tln, wt, bq, bk, bv, qkvb, x, out);
    k3<<<2048, 256, 0, stream>>>(qkvb, wt + (size_t)3 * CC * CC, bo, s_shift, ctxb, out, x);
}